// Round 4
// baseline (625.675 us; speedup 1.0000x reference)
//
#include <hip/hip_runtime.h>
#include <stdint.h>

#define NN   16384
#define HID  256
#define LDSK 264            // padded LDS row stride in f16 elems (gemm_xw only)
#define NSLICE 16           // j sliced 16-way
#define JSL  (NN/NSLICE)    // 1024 j's per slice
#define NSETS 2             // stationary i-sets per wave (R2-proven: no spill, 3 blk/CU)
#define ITILE (NSETS*64)    // 128 i's per block
#define NRS  8              // exact-rescore chains (top-8 of 64 by scan key)
#define FLTMAX 3.402823466e38f
#define KEYMAX 0xFFFFFFFFu
#define VBIAS 131072.0f     // R4: folded into sqj64; keeps v64+B > 0 for ALL pairs incl. self
                            // (v64 >= -64*si > -2^17 by AM-GM), so cvt_u32 is well-defined and
                            // the per-eval self-mask (2 VALU ops) moves to one check in rescore.
#define MSTRIDE 17          // padded merge stride (u32): tid*17 reads are conflict-free

typedef __attribute__((ext_vector_type(8))) _Float16 f16x8;
typedef __attribute__((ext_vector_type(4))) _Float16 f16x4;
typedef __attribute__((ext_vector_type(4))) float f32x4;

typedef const __attribute__((address_space(1))) unsigned int* gAS1;
typedef __attribute__((address_space(3))) unsigned int* lAS3;

// ---- fused fp32->fp16 convert (x, W1, W2) + np-replicating row sum-of-squares ----
// R4: one launch instead of two (launch-count trim).
#define NXG (NN*HID/4)
#define NWG (HID*HID/4)
#define CVTB ((NXG + 2*NWG)/256)     // 4224 cvt blocks
__global__ __launch_bounds__(256) void prep_kernel(const float* __restrict__ x,
                                                   const float* __restrict__ W1,
                                                   const float* __restrict__ W2,
                                                   _Float16* __restrict__ xh,
                                                   _Float16* __restrict__ W1h,
                                                   _Float16* __restrict__ W2h,
                                                   float* __restrict__ sqf){
  #pragma clang fp contract(off)
  int b = blockIdx.x;
  if (b < CVTB){
    int g = b * 256 + threadIdx.x;
    const float* src; _Float16* dst; int o;
    if (g < NXG)            { src = x;  dst = xh;  o = g; }
    else if (g < NXG + NWG) { src = W1; dst = W1h; o = g - NXG; }
    else                    { src = W2; dst = W2h; o = g - NXG - NWG; }
    float4 v = ((const float4*)src)[o];
    f16x4 h; h.x = (_Float16)v.x; h.y = (_Float16)v.y; h.z = (_Float16)v.z; h.w = (_Float16)v.w;
    ((f16x4*)dst)[o] = h;
  } else {
    int bb = b - CVTB;
    int lane = threadIdx.x & 63;
    int rw   = lane >> 4;
    int h    = (lane >> 3) & 1;
    int j    = lane & 7;
    int row  = (bb * 4 + (threadIdx.x >> 6)) * 4 + rw;
    const float* p = x + (size_t)row * HID + h*128 + j;
    float v0 = p[0];
    float r  = v0 * v0;
    #pragma unroll
    for (int i = 1; i < 16; ++i){ float v = p[i*8]; float m = v * v; r = r + m; }
    float t1 = r  + __shfl_xor(r,  1);
    float t2 = t1 + __shfl_xor(t1, 2);
    float t3 = t2 + __shfl_xor(t2, 4);
    float tot = t3 + __shfl_xor(t3, 8);
    if (h == 0 && j == 0) sqf[row] = tot;
  }
}

// stage 64x256 f16 tile into LDS with padded stride (256 threads) — gemm_xw only
__device__ __forceinline__ void load_tile64(unsigned short* dst, const unsigned short* src, int tid){
  const uint4* s = (const uint4*)src;
  #pragma unroll
  for (int r = 0; r < 8; ++r){
    int fl  = tid + (r << 8);
    int row = fl >> 5;
    int c   = fl & 31;
    *(uint4*)&dst[row*LDSK + (c << 3)] = s[fl];
  }
}

// branchless sorted-ascending top-4 insert of a u32 key (R3-proven)
__device__ __forceinline__ void ins4(unsigned (&b)[4], unsigned k){
  unsigned t3 = k > b[2] ? k : b[2];
  unsigned t2 = k > b[1] ? k : b[1];
  unsigned t1 = k > b[0] ? k : b[0];
  b[3] = t3 < b[3] ? t3 : b[3];
  b[2] = t2 < b[2] ? t2 : b[2];
  b[1] = t1 < b[1] ? t1 : b[1];
  b[0] = k  < b[0] ? k  : b[0];
}

// fp16 MFMA Gram, swapped operands, TWO stationary i-sets/wave (R2/R3-proven
// eval semantics). R4 changes, mechanics only:
//  (a) FRAGMENT-MAJOR LDS: j-tile stored as 32 x 1KB fragments, frag f=sub*8+ks,
//      slot s=quad*16+lcol holds row sub*16+lcol, f16 cols [ks*32+quad*8,+8) —
//      identical element->lane mapping as the old row-major read, but ds_read is
//      base+lane*16 with compile-time offset: ZERO bank conflicts (was 8-way:
//      row stride 528B == 16 mod 128 put 8 lanes per bank-quad; 1.74e7 conflict
//      cycles = ~14% of knn). Staged via pre-swizzled GLOBAL addresses +
//      global_load_lds width 16 (linear LDS dest, no VGPR round-trip).
//  (b) VBIAS fold removes the 2-op per-eval self-mask (self = guaranteed rank-0
//      key of its own slice, dropped in rescore). 10 VALU ops/eval.
__global__ __launch_bounds__(256, 3) void knn_kernel(const _Float16* __restrict__ xh,
                                                     const float* __restrict__ sqf,
                                                     unsigned* __restrict__ candk){
  __shared__ __align__(16) unsigned short Xj[64 * 256];   // 32 KB fragment-major; aliased as merge buf
  __shared__ __align__(16) float sqj64[64];               // sq_j*64 + VBIAS

  int tid  = threadIdx.x;
  int sl   = blockIdx.x & (NSLICE-1);
  int i0   = (blockIdx.x / NSLICE) * ITILE;
  int jb0  = sl * JSL;
  int wave = tid >> 6, lane = tid & 63, quad = lane >> 4, lcol = lane & 15;

  f16x8 bfr[NSETS][8];
  #pragma unroll
  for (int s = 0; s < NSETS; ++s){
    const _Float16* br = xh + (size_t)(i0 + s*64 + wave*16 + lcol) * HID + quad*8;
    #pragma unroll
    for (int ks = 0; ks < 8; ++ks) bfr[s][ks] = *(const f16x8*)(br + ks*32);
  }

  // per-thread staging sources: chunk m = r*256+tid; f=m>>6 (sub=f>>3, ks=f&7),
  // s=m&63 (q=s>>4, l=s&15); src row-local = sub*16+l, f16 col = ks*32+q*8.
  // LDS dest = m*16 bytes (linear in lane -> conflict-free global_load_lds).
  const _Float16* gsrc[8];
  #pragma unroll
  for (int r = 0; r < 8; ++r){
    int m = r*256 + tid;
    int f = m >> 6, s = m & 63;
    int row = ((f >> 3) << 4) + (s & 15);
    int col = ((f & 7) << 5) + ((s >> 4) << 3);
    gsrc[r] = xh + (size_t)row * HID + col;
  }

  unsigned bk[NSETS][4];
  #pragma unroll
  for (int s = 0; s < NSETS; ++s)
    #pragma unroll
    for (int e = 0; e < 4; ++e) bk[s][e] = KEYMAX;

  for (int it = 0; it < JSL; it += 64){
    int jb = jb0 + it;
    size_t joff = (size_t)jb * HID;
    __syncthreads();
    #pragma unroll
    for (int r = 0; r < 8; ++r){
      __builtin_amdgcn_global_load_lds((gAS1)(const void*)(gsrc[r] + joff),
                                       (lAS3)(void*)&Xj[(r*256 + tid) * 8],
                                       16, 0, 0);
    }
    if (tid < 64) sqj64[tid] = fmaf(sqf[jb + tid], 64.f, VBIAS);
    __syncthreads();

    #pragma unroll
    for (int sub = 0; sub < 4; ++sub){
      f32x4 acc[NSETS];
      #pragma unroll
      for (int s = 0; s < NSETS; ++s) acc[s] = (f32x4){0.f,0.f,0.f,0.f};
      #pragma unroll
      for (int ks = 0; ks < 8; ++ks){
        f16x8 a = *(const f16x8*)&Xj[(((sub*8 + ks) << 6) + lane) * 8];
        #pragma unroll
        for (int s = 0; s < NSETS; ++s)
          acc[s] = __builtin_amdgcn_mfma_f32_16x16x32_f16(a, bfr[s][ks], acc[s], 0, 0, 0);
      }
      // C: row = j-local-in-tile = quad*4+reg, col = i-local = lcol
      float4 sj4 = *(const float4*)&sqj64[sub*16 + quad*4];
      int jbase = jb + sub*16 + quad*4;
      #pragma unroll
      for (int reg = 0; reg < 4; ++reg){
        int gj = jbase + reg;
        float sj = (&sj4.x)[reg];
        #pragma unroll
        for (int s = 0; s < NSETS; ++s){
          float v64 = fmaf(-128.f, acc[s][reg], sj);   // (sj - 2*dot)*64 + VBIAS > 0 always
          unsigned kv = (unsigned)v64;                 // v_cvt_u32_f32
          unsigned key = (kv << 14) + (unsigned)gj;    // v_lshl_add_u32
          ins4(bk[s], key);
        }
      }
    }
  }

  // merge across the 4 quads per i: 16 keys -> top-4 (LDS aliased on Xj, stride 17)
  __syncthreads();
  unsigned* Mk = (unsigned*)Xj;            // ITILE x 17 u32 = 8704 B (<= 32768)
  #pragma unroll
  for (int s = 0; s < NSETS; ++s){
    int base = (s*64 + wave*16 + lcol)*MSTRIDE + quad*4;
    #pragma unroll
    for (int e = 0; e < 4; ++e) Mk[base+e] = bk[s][e];
  }
  __syncthreads();
  if (tid < ITILE){
    unsigned fk[4];
    #pragma unroll
    for (int e = 0; e < 4; ++e) fk[e] = KEYMAX;
    #pragma unroll
    for (int s = 0; s < 16; ++s) ins4(fk, Mk[tid*MSTRIDE + s]);
    int g = i0 + tid;
    #pragma unroll
    for (int e = 0; e < 4; ++e)
      candk[(size_t)g*(NSLICE*4) + sl*4 + e] = fk[e];
  }
}

// Rescore: mask the self key (rank-0 of its own slice by construction), rank the
// 64 packed scan keys (all distinct: disjoint j + single self), take top-8,
// stage those rows TRANSPOSED in LDS, run the exact np-replicating fp32
// pipeline: dot = sequential-in-k fp32 FMA chain, d2 = fl32(fl32(sq_i+sq_j) -
// 2*dot). Final rank by (d2, index) lex. One wave per node.
__global__ __launch_bounds__(64) void rescore_kernel(const float* __restrict__ x,
                                                     const float* __restrict__ sqf,
                                                     const unsigned* __restrict__ candk,
                                                     int* __restrict__ idx_out,
                                                     int* __restrict__ Bdeg){
  #pragma clang fp contract(off)
  __shared__ float Xi[256];
  __shared__ float Xct[256][NRS+1];   // transposed candidate rows, 9.2 KB
  __shared__ float dex[NRS];
  __shared__ int   sel[NRS];
  int i = blockIdx.x;
  int t = threadIdx.x;            // 0..63
  ((float4*)Xi)[t] = ((const float4*)(x + (size_t)i * HID))[t];
  unsigned kv = candk[(size_t)i*(NSLICE*4) + t];
  if ((kv & 16383u) == (unsigned)i) kv = KEYMAX;   // drop self (R4: moved out of the scan)
  int rank = 0;
  for (int s = 0; s < 64; ++s){
    unsigned ks = __shfl(kv, s);
    rank += (ks < kv) ? 1 : 0;
  }
  if (rank < NRS) sel[rank] = (int)(kv & 16383u);
  __syncthreads();
  {
    int r = t >> 3, seg = t & 7;     // 8 rows x 8 segments
    const float4* src = (const float4*)(x + (size_t)sel[r] * HID);
    #pragma unroll
    for (int m = 0; m < 8; ++m){
      float4 v = src[seg + 8*m];
      int k = 4*(seg + 8*m);
      Xct[k+0][r] = v.x; Xct[k+1][r] = v.y; Xct[k+2][r] = v.z; Xct[k+3][r] = v.w;
    }
  }
  __syncthreads();
  if (t < NRS){
    int j = sel[t];
    float acc = 0.f;
    for (int k = 0; k < 256; ++k) acc = fmaf(Xi[k], Xct[k][t], acc);
    float t1   = sqf[i] + sqf[j];
    float twod = 2.0f * acc;
    dex[t] = t1 - twod;
  }
  __syncthreads();
  if (t == 0){
    unsigned taken = 0;
    #pragma unroll
    for (int k = 0; k < 4; ++k){
      float bdv = FLTMAX; int bj = 0x7fffffff, bs = -1;
      for (int s = 0; s < NRS; ++s){
        if (taken & (1u << s)) continue;
        float d = dex[s]; int j = sel[s];
        if (d < bdv || (d == bdv && j < bj)){ bdv = d; bj = j; bs = s; }
      }
      taken |= 1u << bs;
      idx_out[i*4 + k] = bj;
      atomicAdd(&Bdeg[bj], 1);
    }
  }
}

// out[i][o] = sum_k A[i][k] * W[o][k]   (A: Mx256 f16, W staged f16, out f16)
__global__ __launch_bounds__(256) void gemm_xw(const _Float16* __restrict__ A,
                                               const _Float16* __restrict__ W,
                                               _Float16* __restrict__ out){
  __shared__ unsigned short Ws[64 * LDSK];
  int tid = threadIdx.x;
  int i0 = (blockIdx.x >> 2) * 64;
  int o0 = (blockIdx.x & 3)  * 64;
  int wave = tid >> 6, lane = tid & 63, quad = lane >> 4, lcol = lane & 15;
  load_tile64(Ws, (const unsigned short*)(W + (size_t)o0 * HID), tid);
  f16x8 a[8];
  const _Float16* arow = A + (size_t)(i0 + wave*16 + lcol) * HID + quad*8;
  #pragma unroll
  for (int ks = 0; ks < 8; ++ks) a[ks] = *(const f16x8*)(arow + ks*32);
  __syncthreads();
  #pragma unroll
  for (int sub = 0; sub < 4; ++sub){
    f32x4 acc = {0.f, 0.f, 0.f, 0.f};
    #pragma unroll
    for (int ks = 0; ks < 8; ++ks){
      f16x8 b = *(const f16x8*)&Ws[(sub*16 + lcol)*LDSK + quad*8 + ks*32];
      acc = __builtin_amdgcn_mfma_f32_16x16x32_f16(a[ks], b, acc, 0, 0, 0);
    }
    #pragma unroll
    for (int reg = 0; reg < 4; ++reg)
      out[(size_t)(i0 + wave*16 + quad*4 + reg)*HID + o0 + sub*16 + lcol] = (_Float16)acc[reg];
  }
}

__global__ __launch_bounds__(256) void prefix_kernel(const int* __restrict__ Bdeg,
                                                     int* __restrict__ off,
                                                     int* __restrict__ cursor){
  __shared__ int psum[256];
  __shared__ int excl[256];
  int t = threadIdx.x;
  int base = t * 64;
  int s = 0;
  for (int k = 0; k < 64; ++k) s += Bdeg[base + k];
  psum[t] = s;
  __syncthreads();
  if (t == 0){ int a = 0; for (int k = 0; k < 256; ++k){ excl[k] = a; a += psum[k]; } }
  __syncthreads();
  int a = excl[t];
  for (int k = 0; k < 64; ++k){ int dv = Bdeg[base + k]; off[base+k] = a; cursor[base+k] = a; a += dv; }
}

__global__ __launch_bounds__(256) void fill_kernel(const int* __restrict__ idx,
                                                   int* __restrict__ cursor,
                                                   int* __restrict__ rev){
  int i = blockIdx.x * 256 + threadIdx.x;
  #pragma unroll
  for (int t = 0; t < 4; ++t){
    int e = idx[i*4 + t];
    int p = atomicAdd(&cursor[e], 1);
    rev[p] = i;
  }
}

// E[e] = mean over contributing nodes of xt[node]  (gather via reverse CSR)
__global__ __launch_bounds__(256) void efeat_kernel(const _Float16* __restrict__ xt,
                                                    const int* __restrict__ off,
                                                    const int* __restrict__ deg,
                                                    const int* __restrict__ rev,
                                                    _Float16* __restrict__ E){
  int e = blockIdx.x, c = threadIdx.x;
  int o = off[e], d = deg[e];
  float s = 0.f;
  for (int k = 0; k < d; ++k) s += (float)xt[(size_t)rev[o + k]*HID + c];
  E[(size_t)e*HID + c] = (_Float16)((d > 0) ? s / (float)d : 0.f);
}

__global__ __launch_bounds__(256) void fin1_kernel(const _Float16* __restrict__ E,
                                                   const int* __restrict__ idx,
                                                   const float* __restrict__ b1,
                                                   const float* __restrict__ pa,
                                                   _Float16* __restrict__ h1){
  int i = blockIdx.x, c = threadIdx.x;
  const int* ip = idx + i*4;
  float s = (float)E[(size_t)ip[0]*HID + c] + (float)E[(size_t)ip[1]*HID + c]
          + (float)E[(size_t)ip[2]*HID + c] + (float)E[(size_t)ip[3]*HID + c];
  float acc = 0.25f * s + b1[c];
  float a = pa[0];
  acc = (acc >= 0.f) ? acc : a * acc;
  h1[(size_t)i*HID + c] = (_Float16)acc;
}

__global__ __launch_bounds__(256) void fin2_kernel(const _Float16* __restrict__ E,
                                                   const int* __restrict__ idx,
                                                   const float* __restrict__ b2,
                                                   const float* __restrict__ x,
                                                   const float* __restrict__ pa,
                                                   float* __restrict__ out){
  int i = blockIdx.x, c = threadIdx.x;
  const int* ip = idx + i*4;
  float s = (float)E[(size_t)ip[0]*HID + c] + (float)E[(size_t)ip[1]*HID + c]
          + (float)E[(size_t)ip[2]*HID + c] + (float)E[(size_t)ip[3]*HID + c];
  float acc = 0.25f * s + b2[c] + x[(size_t)i*HID + c];
  float a = pa[0];
  acc = (acc >= 0.f) ? acc : a * acc;
  out[(size_t)i*HID + c] = acc;
}

extern "C" void kernel_launch(void* const* d_in, const int* in_sizes, int n_in,
                              void* d_out, int out_size, void* d_ws, size_t ws_size,
                              hipStream_t stream){
  (void)in_sizes; (void)n_in; (void)out_size; (void)ws_size;
  const float* x  = (const float*)d_in[0];
  // d_in[1] = edge_index (int32), unused by the math
  const float* W1 = (const float*)d_in[2];
  const float* b1 = (const float*)d_in[3];
  const float* W2 = (const float*)d_in[4];
  const float* b2 = (const float*)d_in[5];
  const float* pa = (const float*)d_in[6];
  float* out = (float*)d_out;

  char* ws = (char*)d_ws;
  float*  sqf    = (float*) (ws + 0);                        //  64 KB
  int*    idx    = (int*)   (ws + 65536);                    // 256 KB
  int*    Bdeg   = (int*)   (ws + 327680);                   //  64 KB
  int*    offE   = (int*)   (ws + 393216);                   //  64 KB
  int*    cursor = (int*)   (ws + 458752);                   //  64 KB
  int*    rev    = (int*)   (ws + 524288);                   // 256 KB
  _Float16* xh   = (_Float16*)(ws + (size_t)(5<<20));        //   8 MB
  _Float16* W1h  = (_Float16*)(ws + (size_t)(13<<20));       // 128 KB
  _Float16* W2h  = (_Float16*)(ws + (size_t)(13<<20) + 131072);
  _Float16* xt   = (_Float16*)(ws + (size_t)(13<<20) + 262144);            // 8 MB
  _Float16* E    = (_Float16*)(ws + (size_t)(21<<20) + 262144);            // 8 MB
  _Float16* h1   = (_Float16*)(ws + (size_t)(29<<20) + 262144);            // 8 MB
  // candk (NN*64*4B = 4 MB) aliases the xt region: dead until the first
  // gemm_xw (which runs after rescore consumes it) -> no ws growth.
  unsigned* candk = (unsigned*)xt;                           // 4 MB

  hipMemsetAsync(Bdeg, 0, NN*sizeof(int), stream);
  prep_kernel   <<<CVTB + NN/16, 256, 0, stream>>>(x, W1, W2, xh, W1h, W2h, sqf);
  knn_kernel    <<<(NN/ITILE)*NSLICE, 256, 0, stream>>>(xh, sqf, candk);
  rescore_kernel<<<NN,      64, 0, stream>>>(x, sqf, candk, idx, Bdeg);
  prefix_kernel <<<1,      256, 0, stream>>>(Bdeg, offE, cursor);
  fill_kernel   <<<NN/256, 256, 0, stream>>>(idx, cursor, rev);

  gemm_xw       <<<(NN/64)*4, 256, 0, stream>>>(xh, W1h, xt);
  efeat_kernel  <<<NN,        256, 0, stream>>>(xt, offE, Bdeg, rev, E);
  fin1_kernel   <<<NN,        256, 0, stream>>>(E, idx, b1, pa, h1);

  gemm_xw       <<<(NN/64)*4, 256, 0, stream>>>(h1, W2h, xt);
  efeat_kernel  <<<NN,        256, 0, stream>>>(xt, offE, Bdeg, rev, E);
  fin2_kernel   <<<NN,        256, 0, stream>>>(E, idx, b2, x, pa, out);
}

// Round 5
// 590.702 us; speedup vs baseline: 1.0592x; 1.0592x over previous
//
#include <hip/hip_runtime.h>
#include <stdint.h>

#define NN   16384
#define HID  256
#define LDSK 264            // padded LDS row stride in f16 elems (gemm_xw only)
#define NSLICE 16           // j sliced 16-way
#define JSL  (NN/NSLICE)    // 1024 j's per slice
#define JT   32             // R5: j-tile rows (was 64) -> 16KB tiles, double-buffered
#define NIT  (JSL/JT)       // 32 iterations per block
#define NSETS 2             // stationary i-sets per wave (R2-proven: no spill)
#define ITILE (NSETS*64)    // 128 i's per block
#define NRS  8              // exact-rescore chains (top-8 of 64 by scan key)
#define FLTMAX 3.402823466e38f
#define KEYMAX 0xFFFFFFFFu
#define VBIAS 131072.0f     // folded into sqj64; keeps v64+B > 0 for ALL pairs incl. self
#define MSTRIDE 17          // padded merge stride (u32): tid*17 reads are conflict-free

typedef __attribute__((ext_vector_type(8))) _Float16 f16x8;
typedef __attribute__((ext_vector_type(4))) _Float16 f16x4;
typedef __attribute__((ext_vector_type(4))) float f32x4;

typedef const __attribute__((address_space(1))) unsigned int* gAS1;
typedef __attribute__((address_space(3))) unsigned int* lAS3;

// ---- fused fp32->fp16 convert (x, W1, W2) + np-replicating row sum-of-squares ----
#define NXG (NN*HID/4)
#define NWG (HID*HID/4)
#define CVTB ((NXG + 2*NWG)/256)     // 4224 cvt blocks
__global__ __launch_bounds__(256) void prep_kernel(const float* __restrict__ x,
                                                   const float* __restrict__ W1,
                                                   const float* __restrict__ W2,
                                                   _Float16* __restrict__ xh,
                                                   _Float16* __restrict__ W1h,
                                                   _Float16* __restrict__ W2h,
                                                   float* __restrict__ sqf){
  #pragma clang fp contract(off)
  int b = blockIdx.x;
  if (b < CVTB){
    int g = b * 256 + threadIdx.x;
    const float* src; _Float16* dst; int o;
    if (g < NXG)            { src = x;  dst = xh;  o = g; }
    else if (g < NXG + NWG) { src = W1; dst = W1h; o = g - NXG; }
    else                    { src = W2; dst = W2h; o = g - NXG - NWG; }
    float4 v = ((const float4*)src)[o];
    f16x4 h; h.x = (_Float16)v.x; h.y = (_Float16)v.y; h.z = (_Float16)v.z; h.w = (_Float16)v.w;
    ((f16x4*)dst)[o] = h;
  } else {
    int bb = b - CVTB;
    int lane = threadIdx.x & 63;
    int rw   = lane >> 4;
    int h    = (lane >> 3) & 1;
    int j    = lane & 7;
    int row  = (bb * 4 + (threadIdx.x >> 6)) * 4 + rw;
    const float* p = x + (size_t)row * HID + h*128 + j;
    float v0 = p[0];
    float r  = v0 * v0;
    #pragma unroll
    for (int i = 1; i < 16; ++i){ float v = p[i*8]; float m = v * v; r = r + m; }
    float t1 = r  + __shfl_xor(r,  1);
    float t2 = t1 + __shfl_xor(t1, 2);
    float t3 = t2 + __shfl_xor(t2, 4);
    float tot = t3 + __shfl_xor(t3, 8);
    if (h == 0 && j == 0) sqf[row] = tot;
  }
}

// stage 64x256 f16 tile into LDS with padded stride (256 threads) — gemm_xw only
__device__ __forceinline__ void load_tile64(unsigned short* dst, const unsigned short* src, int tid){
  const uint4* s = (const uint4*)src;
  #pragma unroll
  for (int r = 0; r < 8; ++r){
    int fl  = tid + (r << 8);
    int row = fl >> 5;
    int c   = fl & 31;
    *(uint4*)&dst[row*LDSK + (c << 3)] = s[fl];
  }
}

// branchless sorted-ascending top-4 insert of a u32 key (R3-proven)
__device__ __forceinline__ void ins4(unsigned (&b)[4], unsigned k){
  unsigned t3 = k > b[2] ? k : b[2];
  unsigned t2 = k > b[1] ? k : b[1];
  unsigned t1 = k > b[0] ? k : b[0];
  b[3] = t3 < b[3] ? t3 : b[3];
  b[2] = t2 < b[2] ? t2 : b[2];
  b[1] = t1 < b[1] ? t1 : b[1];
  b[0] = k  < b[0] ? k  : b[0];
}

// fp16 MFMA Gram, swapped operands, TWO stationary i-sets/wave. R3-proven eval
// semantics (packed u32 key, VBIAS fold, self dropped in rescore). R5 mechanics:
//  (a) XOR-SWIZZLED ROW-MAJOR LDS: tile row-major, 512B rows, 16B chunk at
//      ch_lds = ch_src ^ (row&7). Reads are conflict-free (within each
//      8-consecutive-lane pass the bank group (q^(l&3), (ks&1)^((l>>2)&1))
//      takes all 8 values), AND the inverse-swizzled global source permutes
//      chunks only WITHIN each 512B row -> staging stays line-coalesced
//      (R4's fragment-major source gathered 16x64B from 16 rows -> latency).
//  (b) DOUBLE-BUFFERED 32-row tiles, prefetch-before-compute: next tile's
//      global_load_lds issued BEFORE computing current; the barrier's implicit
//      vmcnt(0) then waits on loads a full compute phase old -> drain ~ 0
//      (R4 single-buffer exposed full load latency at every barrier).
//      2x16KB+eps = 33KB LDS -> 4 blocks/CU; VGPR ~110 -> bounds (256,4) safe.
__global__ __launch_bounds__(256, 4) void knn_kernel(const _Float16* __restrict__ xh,
                                                     const float* __restrict__ sqf,
                                                     unsigned* __restrict__ candk){
  __shared__ __align__(16) unsigned short Xj[2][JT*256];  // 2 x 16KB swizzled tiles; aliased as merge buf
  __shared__ __align__(16) float sqj64[2][JT];            // sq_j*64 + VBIAS, double-buffered

  int tid  = threadIdx.x;
  int sl   = blockIdx.x & (NSLICE-1);
  int i0   = (blockIdx.x / NSLICE) * ITILE;
  int jb0  = sl * JSL;
  int wave = tid >> 6, lane = tid & 63, quad = lane >> 4, lcol = lane & 15;

  f16x8 bfr[NSETS][8];
  #pragma unroll
  for (int s = 0; s < NSETS; ++s){
    const _Float16* br = xh + (size_t)(i0 + s*64 + wave*16 + lcol) * HID + quad*8;
    #pragma unroll
    for (int ks = 0; ks < 8; ++ks) bfr[s][ks] = *(const f16x8*)(br + ks*32);
  }

  // staging sources: LDS chunk m = r*256+tid -> tile row m>>5, lds-chunk m&31,
  // source chunk = (m&31) ^ (row&7)  (inverse swizzle, within-row -> coalesced)
  const _Float16* gsrc[4];
  #pragma unroll
  for (int r = 0; r < 4; ++r){
    int m   = r*256 + tid;
    int row = m >> 5;
    int ch  = m & 31;
    gsrc[r] = xh + (size_t)row * HID + ((ch ^ (row & 7)) << 3);
  }

  // per-lane swizzled read bases (bytes within one tile buffer):
  // addr(sub,ks) = sub*8192 + (ks>>1)*128 + (ks&1 ? b1 : b0)
  int b0 = lcol*512 + ((quad ^ (lcol & 3)) << 4) + (((lcol >> 2) & 1) << 6);
  int b1 = b0 ^ 64;

  unsigned bk[NSETS][4];
  #pragma unroll
  for (int s = 0; s < NSETS; ++s)
    #pragma unroll
    for (int e = 0; e < 4; ++e) bk[s][e] = KEYMAX;

  // prologue: stage tile 0 into buffer 0
  {
    size_t joff = (size_t)jb0 * HID;
    #pragma unroll
    for (int r = 0; r < 4; ++r)
      __builtin_amdgcn_global_load_lds((gAS1)(const void*)(gsrc[r] + joff),
                                       (lAS3)(void*)&Xj[0][(r*256 + tid) * 8],
                                       16, 0, 0);
    if (tid < JT) sqj64[0][tid] = fmaf(sqf[jb0 + tid], 64.f, VBIAS);
  }
  __syncthreads();

  for (int it = 0; it < NIT; ++it){
    // prefetch next tile into the other buffer (issued before compute)
    if (it + 1 < NIT){
      int nb = (it + 1) & 1;
      int jn = jb0 + (it + 1) * JT;
      size_t joff = (size_t)jn * HID;
      #pragma unroll
      for (int r = 0; r < 4; ++r)
        __builtin_amdgcn_global_load_lds((gAS1)(const void*)(gsrc[r] + joff),
                                         (lAS3)(void*)&Xj[nb][(r*256 + tid) * 8],
                                         16, 0, 0);
      if (tid < JT) sqj64[nb][tid] = fmaf(sqf[jn + tid], 64.f, VBIAS);
    }

    const char*  tb  = (const char*)&Xj[it & 1][0];
    const float* sjb = sqj64[it & 1];
    int jb = jb0 + it * JT;

    #pragma unroll
    for (int sub = 0; sub < 2; ++sub){
      f32x4 acc[NSETS];
      #pragma unroll
      for (int s = 0; s < NSETS; ++s) acc[s] = (f32x4){0.f,0.f,0.f,0.f};
      #pragma unroll
      for (int ks = 0; ks < 8; ++ks){
        f16x8 a = *(const f16x8*)(tb + sub*8192 + ((ks >> 1) << 7) + ((ks & 1) ? b1 : b0));
        #pragma unroll
        for (int s = 0; s < NSETS; ++s)
          acc[s] = __builtin_amdgcn_mfma_f32_16x16x32_f16(a, bfr[s][ks], acc[s], 0, 0, 0);
      }
      // C: row = j-local-in-tile = quad*4+reg, col = i-local = lcol
      float4 sj4 = *(const float4*)&sjb[sub*16 + quad*4];
      int jbase = jb + sub*16 + quad*4;
      #pragma unroll
      for (int reg = 0; reg < 4; ++reg){
        int gj = jbase + reg;
        float sj = (&sj4.x)[reg];
        #pragma unroll
        for (int s = 0; s < NSETS; ++s){
          float v64 = fmaf(-128.f, acc[s][reg], sj);   // (sj - 2*dot)*64 + VBIAS > 0 always
          unsigned kv = (unsigned)v64;                 // v_cvt_u32_f32
          unsigned key = (kv << 14) + (unsigned)gj;    // v_lshl_add_u32
          ins4(bk[s], key);
        }
      }
    }
    __syncthreads();   // implicit vmcnt(0): drains the prefetch issued ABOVE (old)
  }

  // merge across the 4 quads per i: 16 keys -> top-4 (LDS aliased on Xj, stride 17)
  unsigned* Mk = (unsigned*)Xj;            // ITILE x 17 u32 = 8704 B (<= 32768)
  #pragma unroll
  for (int s = 0; s < NSETS; ++s){
    int base = (s*64 + wave*16 + lcol)*MSTRIDE + quad*4;
    #pragma unroll
    for (int e = 0; e < 4; ++e) Mk[base+e] = bk[s][e];
  }
  __syncthreads();
  if (tid < ITILE){
    unsigned fk[4];
    #pragma unroll
    for (int e = 0; e < 4; ++e) fk[e] = KEYMAX;
    #pragma unroll
    for (int s = 0; s < 16; ++s) ins4(fk, Mk[tid*MSTRIDE + s]);
    int g = i0 + tid;
    #pragma unroll
    for (int e = 0; e < 4; ++e)
      candk[(size_t)g*(NSLICE*4) + sl*4 + e] = fk[e];
  }
}

// Rescore: mask the self key, rank the 64 packed scan keys, take top-8,
// stage those rows TRANSPOSED in LDS, run the exact np-replicating fp32
// pipeline: dot = sequential-in-k fp32 FMA chain, d2 = fl32(fl32(sq_i+sq_j) -
// 2*dot). Final rank by (d2, index) lex. One wave per node.
__global__ __launch_bounds__(64) void rescore_kernel(const float* __restrict__ x,
                                                     const float* __restrict__ sqf,
                                                     const unsigned* __restrict__ candk,
                                                     int* __restrict__ idx_out,
                                                     int* __restrict__ Bdeg){
  #pragma clang fp contract(off)
  __shared__ float Xi[256];
  __shared__ float Xct[256][NRS+1];   // transposed candidate rows, 9.2 KB
  __shared__ float dex[NRS];
  __shared__ int   sel[NRS];
  int i = blockIdx.x;
  int t = threadIdx.x;            // 0..63
  ((float4*)Xi)[t] = ((const float4*)(x + (size_t)i * HID))[t];
  unsigned kv = candk[(size_t)i*(NSLICE*4) + t];
  if ((kv & 16383u) == (unsigned)i) kv = KEYMAX;   // drop self
  int rank = 0;
  for (int s = 0; s < 64; ++s){
    unsigned ks = __shfl(kv, s);
    rank += (ks < kv) ? 1 : 0;
  }
  if (rank < NRS) sel[rank] = (int)(kv & 16383u);
  __syncthreads();
  {
    int r = t >> 3, seg = t & 7;     // 8 rows x 8 segments
    const float4* src = (const float4*)(x + (size_t)sel[r] * HID);
    #pragma unroll
    for (int m = 0; m < 8; ++m){
      float4 v = src[seg + 8*m];
      int k = 4*(seg + 8*m);
      Xct[k+0][r] = v.x; Xct[k+1][r] = v.y; Xct[k+2][r] = v.z; Xct[k+3][r] = v.w;
    }
  }
  __syncthreads();
  if (t < NRS){
    int j = sel[t];
    float acc = 0.f;
    for (int k = 0; k < 256; ++k) acc = fmaf(Xi[k], Xct[k][t], acc);
    float t1   = sqf[i] + sqf[j];
    float twod = 2.0f * acc;
    dex[t] = t1 - twod;
  }
  __syncthreads();
  if (t == 0){
    unsigned taken = 0;
    #pragma unroll
    for (int k = 0; k < 4; ++k){
      float bdv = FLTMAX; int bj = 0x7fffffff, bs = -1;
      for (int s = 0; s < NRS; ++s){
        if (taken & (1u << s)) continue;
        float d = dex[s]; int j = sel[s];
        if (d < bdv || (d == bdv && j < bj)){ bdv = d; bj = j; bs = s; }
      }
      taken |= 1u << bs;
      idx_out[i*4 + k] = bj;
      atomicAdd(&Bdeg[bj], 1);
    }
  }
}

// out[i][o] = sum_k A[i][k] * W[o][k]   (A: Mx256 f16, W staged f16, out f16)
__global__ __launch_bounds__(256) void gemm_xw(const _Float16* __restrict__ A,
                                               const _Float16* __restrict__ W,
                                               _Float16* __restrict__ out){
  __shared__ unsigned short Ws[64 * LDSK];
  int tid = threadIdx.x;
  int i0 = (blockIdx.x >> 2) * 64;
  int o0 = (blockIdx.x & 3)  * 64;
  int wave = tid >> 6, lane = tid & 63, quad = lane >> 4, lcol = lane & 15;
  load_tile64(Ws, (const unsigned short*)(W + (size_t)o0 * HID), tid);
  f16x8 a[8];
  const _Float16* arow = A + (size_t)(i0 + wave*16 + lcol) * HID + quad*8;
  #pragma unroll
  for (int ks = 0; ks < 8; ++ks) a[ks] = *(const f16x8*)(arow + ks*32);
  __syncthreads();
  #pragma unroll
  for (int sub = 0; sub < 4; ++sub){
    f32x4 acc = {0.f, 0.f, 0.f, 0.f};
    #pragma unroll
    for (int ks = 0; ks < 8; ++ks){
      f16x8 b = *(const f16x8*)&Ws[(sub*16 + lcol)*LDSK + quad*8 + ks*32];
      acc = __builtin_amdgcn_mfma_f32_16x16x32_f16(a[ks], b, acc, 0, 0, 0);
    }
    #pragma unroll
    for (int reg = 0; reg < 4; ++reg)
      out[(size_t)(i0 + wave*16 + quad*4 + reg)*HID + o0 + sub*16 + lcol] = (_Float16)acc[reg];
  }
}

__global__ __launch_bounds__(256) void prefix_kernel(const int* __restrict__ Bdeg,
                                                     int* __restrict__ off,
                                                     int* __restrict__ cursor){
  __shared__ int psum[256];
  __shared__ int excl[256];
  int t = threadIdx.x;
  int base = t * 64;
  int s = 0;
  for (int k = 0; k < 64; ++k) s += Bdeg[base + k];
  psum[t] = s;
  __syncthreads();
  if (t == 0){ int a = 0; for (int k = 0; k < 256; ++k){ excl[k] = a; a += psum[k]; } }
  __syncthreads();
  int a = excl[t];
  for (int k = 0; k < 64; ++k){ int dv = Bdeg[base + k]; off[base+k] = a; cursor[base+k] = a; a += dv; }
}

__global__ __launch_bounds__(256) void fill_kernel(const int* __restrict__ idx,
                                                   int* __restrict__ cursor,
                                                   int* __restrict__ rev){
  int i = blockIdx.x * 256 + threadIdx.x;
  #pragma unroll
  for (int t = 0; t < 4; ++t){
    int e = idx[i*4 + t];
    int p = atomicAdd(&cursor[e], 1);
    rev[p] = i;
  }
}

// E[e] = mean over contributing nodes of xt[node]  (gather via reverse CSR)
__global__ __launch_bounds__(256) void efeat_kernel(const _Float16* __restrict__ xt,
                                                    const int* __restrict__ off,
                                                    const int* __restrict__ deg,
                                                    const int* __restrict__ rev,
                                                    _Float16* __restrict__ E){
  int e = blockIdx.x, c = threadIdx.x;
  int o = off[e], d = deg[e];
  float s = 0.f;
  for (int k = 0; k < d; ++k) s += (float)xt[(size_t)rev[o + k]*HID + c];
  E[(size_t)e*HID + c] = (_Float16)((d > 0) ? s / (float)d : 0.f);
}

__global__ __launch_bounds__(256) void fin1_kernel(const _Float16* __restrict__ E,
                                                   const int* __restrict__ idx,
                                                   const float* __restrict__ b1,
                                                   const float* __restrict__ pa,
                                                   _Float16* __restrict__ h1){
  int i = blockIdx.x, c = threadIdx.x;
  const int* ip = idx + i*4;
  float s = (float)E[(size_t)ip[0]*HID + c] + (float)E[(size_t)ip[1]*HID + c]
          + (float)E[(size_t)ip[2]*HID + c] + (float)E[(size_t)ip[3]*HID + c];
  float acc = 0.25f * s + b1[c];
  float a = pa[0];
  acc = (acc >= 0.f) ? acc : a * acc;
  h1[(size_t)i*HID + c] = (_Float16)acc;
}

__global__ __launch_bounds__(256) void fin2_kernel(const _Float16* __restrict__ E,
                                                   const int* __restrict__ idx,
                                                   const float* __restrict__ b2,
                                                   const float* __restrict__ x,
                                                   const float* __restrict__ pa,
                                                   float* __restrict__ out){
  int i = blockIdx.x, c = threadIdx.x;
  const int* ip = idx + i*4;
  float s = (float)E[(size_t)ip[0]*HID + c] + (float)E[(size_t)ip[1]*HID + c]
          + (float)E[(size_t)ip[2]*HID + c] + (float)E[(size_t)ip[3]*HID + c];
  float acc = 0.25f * s + b2[c] + x[(size_t)i*HID + c];
  float a = pa[0];
  acc = (acc >= 0.f) ? acc : a * acc;
  out[(size_t)i*HID + c] = acc;
}

extern "C" void kernel_launch(void* const* d_in, const int* in_sizes, int n_in,
                              void* d_out, int out_size, void* d_ws, size_t ws_size,
                              hipStream_t stream){
  (void)in_sizes; (void)n_in; (void)out_size; (void)ws_size;
  const float* x  = (const float*)d_in[0];
  // d_in[1] = edge_index (int32), unused by the math
  const float* W1 = (const float*)d_in[2];
  const float* b1 = (const float*)d_in[3];
  const float* W2 = (const float*)d_in[4];
  const float* b2 = (const float*)d_in[5];
  const float* pa = (const float*)d_in[6];
  float* out = (float*)d_out;

  char* ws = (char*)d_ws;
  float*  sqf    = (float*) (ws + 0);                        //  64 KB
  int*    idx    = (int*)   (ws + 65536);                    // 256 KB
  int*    Bdeg   = (int*)   (ws + 327680);                   //  64 KB
  int*    offE   = (int*)   (ws + 393216);                   //  64 KB
  int*    cursor = (int*)   (ws + 458752);                   //  64 KB
  int*    rev    = (int*)   (ws + 524288);                   // 256 KB
  _Float16* xh   = (_Float16*)(ws + (size_t)(5<<20));        //   8 MB
  _Float16* W1h  = (_Float16*)(ws + (size_t)(13<<20));       // 128 KB
  _Float16* W2h  = (_Float16*)(ws + (size_t)(13<<20) + 131072);
  _Float16* xt   = (_Float16*)(ws + (size_t)(13<<20) + 262144);            // 8 MB
  _Float16* E    = (_Float16*)(ws + (size_t)(21<<20) + 262144);            // 8 MB
  _Float16* h1   = (_Float16*)(ws + (size_t)(29<<20) + 262144);            // 8 MB
  // candk (NN*64*4B = 4 MB) aliases the xt region: dead until the first
  // gemm_xw (which runs after rescore consumes it) -> no ws growth.
  unsigned* candk = (unsigned*)xt;                           // 4 MB

  hipMemsetAsync(Bdeg, 0, NN*sizeof(int), stream);
  prep_kernel   <<<CVTB + NN/16, 256, 0, stream>>>(x, W1, W2, xh, W1h, W2h, sqf);
  knn_kernel    <<<(NN/ITILE)*NSLICE, 256, 0, stream>>>(xh, sqf, candk);
  rescore_kernel<<<NN,      64, 0, stream>>>(x, sqf, candk, idx, Bdeg);
  prefix_kernel <<<1,      256, 0, stream>>>(Bdeg, offE, cursor);
  fill_kernel   <<<NN/256, 256, 0, stream>>>(idx, cursor, rev);

  gemm_xw       <<<(NN/64)*4, 256, 0, stream>>>(xh, W1h, xt);
  efeat_kernel  <<<NN,        256, 0, stream>>>(xt, offE, Bdeg, rev, E);
  fin1_kernel   <<<NN,        256, 0, stream>>>(E, idx, b1, pa, h1);

  gemm_xw       <<<(NN/64)*4, 256, 0, stream>>>(h1, W2h, xt);
  efeat_kernel  <<<NN,        256, 0, stream>>>(xt, offE, Bdeg, rev, E);
  fin2_kernel   <<<NN,        256, 0, stream>>>(E, idx, b2, x, pa, out);
}

// Round 6
// 575.164 us; speedup vs baseline: 1.0878x; 1.0270x over previous
//
#include <hip/hip_runtime.h>
#include <stdint.h>

#define NN   16384
#define HID  256
#define LDSK 264            // padded LDS row stride in f16 elems (gemm_xw only)
#define NSLICE 16           // j sliced 16-way
#define JSL  (NN/NSLICE)    // 1024 j's per slice
#define JT   32             // j-tile rows, 16KB tiles, double-buffered (R5-proven)
#define NIT  (JSL/JT)       // 32 iterations per block
#define NSETS 4             // R6: 2 -> 4. LDS bytes/eval halve (a-frag feeds 4 MFMA chains).
                            // R1's spill was launch_bounds(256,4) cap=128 < bfr alone; here
                            // (256,2) cap ~256 >= ~195 demand -> no spill (anti-R1).
#define ITILE (NSETS*64)    // 256 i's per block
#define NRS  8              // exact-rescore chains (top-8 of 64 by scan key)
#define FLTMAX 3.402823466e38f
#define KEYMAX 0xFFFFFFFFu
#define VBIAS 131072.0f     // folded into sqj64; keeps v64+B > 0 for ALL pairs incl. self
#define MSTRIDE 17          // padded merge stride (u32): tid*17 reads are conflict-free

typedef __attribute__((ext_vector_type(8))) _Float16 f16x8;
typedef __attribute__((ext_vector_type(4))) _Float16 f16x4;
typedef __attribute__((ext_vector_type(4))) float f32x4;

typedef const __attribute__((address_space(1))) unsigned int* gAS1;
typedef __attribute__((address_space(3))) unsigned int* lAS3;

// ---- fused fp32->fp16 convert (x, W1, W2) + np-replicating row sum-of-squares ----
#define NXG (NN*HID/4)
#define NWG (HID*HID/4)
#define CVTB ((NXG + 2*NWG)/256)     // 4224 cvt blocks
__global__ __launch_bounds__(256) void prep_kernel(const float* __restrict__ x,
                                                   const float* __restrict__ W1,
                                                   const float* __restrict__ W2,
                                                   _Float16* __restrict__ xh,
                                                   _Float16* __restrict__ W1h,
                                                   _Float16* __restrict__ W2h,
                                                   float* __restrict__ sqf){
  #pragma clang fp contract(off)
  int b = blockIdx.x;
  if (b < CVTB){
    int g = b * 256 + threadIdx.x;
    const float* src; _Float16* dst; int o;
    if (g < NXG)            { src = x;  dst = xh;  o = g; }
    else if (g < NXG + NWG) { src = W1; dst = W1h; o = g - NXG; }
    else                    { src = W2; dst = W2h; o = g - NXG - NWG; }
    float4 v = ((const float4*)src)[o];
    f16x4 h; h.x = (_Float16)v.x; h.y = (_Float16)v.y; h.z = (_Float16)v.z; h.w = (_Float16)v.w;
    ((f16x4*)dst)[o] = h;
  } else {
    int bb = b - CVTB;
    int lane = threadIdx.x & 63;
    int rw   = lane >> 4;
    int h    = (lane >> 3) & 1;
    int j    = lane & 7;
    int row  = (bb * 4 + (threadIdx.x >> 6)) * 4 + rw;
    const float* p = x + (size_t)row * HID + h*128 + j;
    float v0 = p[0];
    float r  = v0 * v0;
    #pragma unroll
    for (int i = 1; i < 16; ++i){ float v = p[i*8]; float m = v * v; r = r + m; }
    float t1 = r  + __shfl_xor(r,  1);
    float t2 = t1 + __shfl_xor(t1, 2);
    float t3 = t2 + __shfl_xor(t2, 4);
    float tot = t3 + __shfl_xor(t3, 8);
    if (h == 0 && j == 0) sqf[row] = tot;
  }
}

// stage 64x256 f16 tile into LDS with padded stride (256 threads) — gemm_xw only
__device__ __forceinline__ void load_tile64(unsigned short* dst, const unsigned short* src, int tid){
  const uint4* s = (const uint4*)src;
  #pragma unroll
  for (int r = 0; r < 8; ++r){
    int fl  = tid + (r << 8);
    int row = fl >> 5;
    int c   = fl & 31;
    *(uint4*)&dst[row*LDSK + (c << 3)] = s[fl];
  }
}

// R6: 4-op sorted-ascending top-4 insert. Identity with the 7-op min/max
// cascade: b0'=min(k,b0); bN'=min(max(k,b(N-1)),bN)=med3(k,b(N-1),bN).
// v_med3_u32 forced via inline asm (VOP3, all-VGPR operands; d==src legal).
__device__ __forceinline__ unsigned umed3(unsigned a, unsigned b, unsigned c){
  unsigned d;
  asm("v_med3_u32 %0, %1, %2, %3" : "=v"(d) : "v"(a), "v"(b), "v"(c));
  return d;
}
__device__ __forceinline__ void ins4(unsigned (&b)[4], unsigned k){
  unsigned b0 = b[0], b1 = b[1], b2 = b[2];
  b[0] = k < b0 ? k : b0;          // v_min_u32
  b[1] = umed3(k, b0, b1);
  b[2] = umed3(k, b1, b2);
  b[3] = umed3(k, b2, b[3]);
}

// fp16 MFMA Gram, swapped operands, FOUR stationary i-sets/wave (R6).
// R5 pipe accounting: LDS-read 82us + MFMA 62us + VALU ~46us ~= 182us observed
// (additive) -> LDS unit is the largest consumer. NSETS 2->4 halves LDS
// bytes/eval (each a-frag read feeds 4 MFMA chains). launch_bounds(256,2):
// generous reg cap (~256) so bfr[4][8] (128 regs, AGPR-parked) cannot spill —
// R1's regression was the (256,4) cap of 128. Eval semantics unchanged
// (packed u32 key, VBIAS fold, self dropped in rescore).
__global__ __launch_bounds__(256, 2) void knn_kernel(const _Float16* __restrict__ xh,
                                                     const float* __restrict__ sqf,
                                                     unsigned* __restrict__ candk){
  __shared__ __align__(16) unsigned short Xj[2][JT*256];  // 2 x 16KB swizzled tiles; aliased as merge buf
  __shared__ __align__(16) float sqj64[2][JT];            // sq_j*64 + VBIAS, double-buffered

  int tid  = threadIdx.x;
  int sl   = blockIdx.x & (NSLICE-1);
  int i0   = (blockIdx.x / NSLICE) * ITILE;
  int jb0  = sl * JSL;
  int wave = tid >> 6, lane = tid & 63, quad = lane >> 4, lcol = lane & 15;

  f16x8 bfr[NSETS][8];
  #pragma unroll
  for (int s = 0; s < NSETS; ++s){
    const _Float16* br = xh + (size_t)(i0 + s*64 + wave*16 + lcol) * HID + quad*8;
    #pragma unroll
    for (int ks = 0; ks < 8; ++ks) bfr[s][ks] = *(const f16x8*)(br + ks*32);
  }

  // staging sources: LDS chunk m = r*256+tid -> tile row m>>5, lds-chunk m&31,
  // source chunk = (m&31) ^ (row&7)  (inverse swizzle, within-row -> coalesced)
  const _Float16* gsrc[4];
  #pragma unroll
  for (int r = 0; r < 4; ++r){
    int m   = r*256 + tid;
    int row = m >> 5;
    int ch  = m & 31;
    gsrc[r] = xh + (size_t)row * HID + ((ch ^ (row & 7)) << 3);
  }

  // per-lane swizzled read bases (bytes within one tile buffer):
  // addr(sub,ks) = sub*8192 + (ks>>1)*128 + (ks&1 ? b1 : b0)
  int b0 = lcol*512 + ((quad ^ (lcol & 3)) << 4) + (((lcol >> 2) & 1) << 6);
  int b1 = b0 ^ 64;

  unsigned bk[NSETS][4];
  #pragma unroll
  for (int s = 0; s < NSETS; ++s)
    #pragma unroll
    for (int e = 0; e < 4; ++e) bk[s][e] = KEYMAX;

  // prologue: stage tile 0 into buffer 0
  {
    size_t joff = (size_t)jb0 * HID;
    #pragma unroll
    for (int r = 0; r < 4; ++r)
      __builtin_amdgcn_global_load_lds((gAS1)(const void*)(gsrc[r] + joff),
                                       (lAS3)(void*)&Xj[0][(r*256 + tid) * 8],
                                       16, 0, 0);
    if (tid < JT) sqj64[0][tid] = fmaf(sqf[jb0 + tid], 64.f, VBIAS);
  }
  __syncthreads();

  for (int it = 0; it < NIT; ++it){
    // prefetch next tile into the other buffer (issued before compute)
    if (it + 1 < NIT){
      int nb = (it + 1) & 1;
      int jn = jb0 + (it + 1) * JT;
      size_t joff = (size_t)jn * HID;
      #pragma unroll
      for (int r = 0; r < 4; ++r)
        __builtin_amdgcn_global_load_lds((gAS1)(const void*)(gsrc[r] + joff),
                                         (lAS3)(void*)&Xj[nb][(r*256 + tid) * 8],
                                         16, 0, 0);
      if (tid < JT) sqj64[nb][tid] = fmaf(sqf[jn + tid], 64.f, VBIAS);
    }

    const char*  tb  = (const char*)&Xj[it & 1][0];
    const float* sjb = sqj64[it & 1];
    int jb = jb0 + it * JT;

    #pragma unroll
    for (int sub = 0; sub < 2; ++sub){
      f32x4 acc[NSETS];
      #pragma unroll
      for (int s = 0; s < NSETS; ++s) acc[s] = (f32x4){0.f,0.f,0.f,0.f};
      #pragma unroll
      for (int ks = 0; ks < 8; ++ks){
        f16x8 a = *(const f16x8*)(tb + sub*8192 + ((ks >> 1) << 7) + ((ks & 1) ? b1 : b0));
        #pragma unroll
        for (int s = 0; s < NSETS; ++s)
          acc[s] = __builtin_amdgcn_mfma_f32_16x16x32_f16(a, bfr[s][ks], acc[s], 0, 0, 0);
      }
      // C: row = j-local-in-tile = quad*4+reg, col = i-local = lcol
      float4 sj4 = *(const float4*)&sjb[sub*16 + quad*4];
      int jbase = jb + sub*16 + quad*4;
      #pragma unroll
      for (int reg = 0; reg < 4; ++reg){
        int gj = jbase + reg;
        float sj = (&sj4.x)[reg];
        #pragma unroll
        for (int s = 0; s < NSETS; ++s){
          float v64 = fmaf(-128.f, acc[s][reg], sj);   // (sj - 2*dot)*64 + VBIAS > 0 always
          unsigned kv = (unsigned)v64;                 // v_cvt_u32_f32
          unsigned key = (kv << 14) + (unsigned)gj;    // v_lshl_add_u32
          ins4(bk[s], key);
        }
      }
    }
    __syncthreads();   // implicit vmcnt(0): drains the prefetch issued ABOVE (old)
  }

  // merge across the 4 quads per i: 16 keys -> top-4 (LDS aliased on Xj, stride 17)
  unsigned* Mk = (unsigned*)Xj;            // ITILE x 17 u32 = 17408 B (<= 32768)
  #pragma unroll
  for (int s = 0; s < NSETS; ++s){
    int base = (s*64 + wave*16 + lcol)*MSTRIDE + quad*4;
    #pragma unroll
    for (int e = 0; e < 4; ++e) Mk[base+e] = bk[s][e];
  }
  __syncthreads();
  if (tid < ITILE){
    unsigned fk[4];
    #pragma unroll
    for (int e = 0; e < 4; ++e) fk[e] = KEYMAX;
    #pragma unroll
    for (int s = 0; s < 16; ++s) ins4(fk, Mk[tid*MSTRIDE + s]);
    int g = i0 + tid;
    #pragma unroll
    for (int e = 0; e < 4; ++e)
      candk[(size_t)g*(NSLICE*4) + sl*4 + e] = fk[e];
  }
}

// Rescore: mask the self key, rank the 64 packed scan keys, take top-8,
// stage those rows TRANSPOSED in LDS, run the exact np-replicating fp32
// pipeline: dot = sequential-in-k fp32 FMA chain, d2 = fl32(fl32(sq_i+sq_j) -
// 2*dot). Final rank by (d2, index) lex. One wave per node.
__global__ __launch_bounds__(64) void rescore_kernel(const float* __restrict__ x,
                                                     const float* __restrict__ sqf,
                                                     const unsigned* __restrict__ candk,
                                                     int* __restrict__ idx_out,
                                                     int* __restrict__ Bdeg){
  #pragma clang fp contract(off)
  __shared__ float Xi[256];
  __shared__ float Xct[256][NRS+1];   // transposed candidate rows, 9.2 KB
  __shared__ float dex[NRS];
  __shared__ int   sel[NRS];
  int i = blockIdx.x;
  int t = threadIdx.x;            // 0..63
  ((float4*)Xi)[t] = ((const float4*)(x + (size_t)i * HID))[t];
  unsigned kv = candk[(size_t)i*(NSLICE*4) + t];
  if ((kv & 16383u) == (unsigned)i) kv = KEYMAX;   // drop self
  int rank = 0;
  for (int s = 0; s < 64; ++s){
    unsigned ks = __shfl(kv, s);
    rank += (ks < kv) ? 1 : 0;
  }
  if (rank < NRS) sel[rank] = (int)(kv & 16383u);
  __syncthreads();
  {
    int r = t >> 3, seg = t & 7;     // 8 rows x 8 segments
    const float4* src = (const float4*)(x + (size_t)sel[r] * HID);
    #pragma unroll
    for (int m = 0; m < 8; ++m){
      float4 v = src[seg + 8*m];
      int k = 4*(seg + 8*m);
      Xct[k+0][r] = v.x; Xct[k+1][r] = v.y; Xct[k+2][r] = v.z; Xct[k+3][r] = v.w;
    }
  }
  __syncthreads();
  if (t < NRS){
    int j = sel[t];
    float acc = 0.f;
    for (int k = 0; k < 256; ++k) acc = fmaf(Xi[k], Xct[k][t], acc);
    float t1   = sqf[i] + sqf[j];
    float twod = 2.0f * acc;
    dex[t] = t1 - twod;
  }
  __syncthreads();
  if (t == 0){
    unsigned taken = 0;
    #pragma unroll
    for (int k = 0; k < 4; ++k){
      float bdv = FLTMAX; int bj = 0x7fffffff, bs = -1;
      for (int s = 0; s < NRS; ++s){
        if (taken & (1u << s)) continue;
        float d = dex[s]; int j = sel[s];
        if (d < bdv || (d == bdv && j < bj)){ bdv = d; bj = j; bs = s; }
      }
      taken |= 1u << bs;
      idx_out[i*4 + k] = bj;
      atomicAdd(&Bdeg[bj], 1);
    }
  }
}

// out[i][o] = sum_k A[i][k] * W[o][k]   (A: Mx256 f16, W staged f16, out f16)
__global__ __launch_bounds__(256) void gemm_xw(const _Float16* __restrict__ A,
                                               const _Float16* __restrict__ W,
                                               _Float16* __restrict__ out){
  __shared__ unsigned short Ws[64 * LDSK];
  int tid = threadIdx.x;
  int i0 = (blockIdx.x >> 2) * 64;
  int o0 = (blockIdx.x & 3)  * 64;
  int wave = tid >> 6, lane = tid & 63, quad = lane >> 4, lcol = lane & 15;
  load_tile64(Ws, (const unsigned short*)(W + (size_t)o0 * HID), tid);
  f16x8 a[8];
  const _Float16* arow = A + (size_t)(i0 + wave*16 + lcol) * HID + quad*8;
  #pragma unroll
  for (int ks = 0; ks < 8; ++ks) a[ks] = *(const f16x8*)(arow + ks*32);
  __syncthreads();
  #pragma unroll
  for (int sub = 0; sub < 4; ++sub){
    f32x4 acc = {0.f, 0.f, 0.f, 0.f};
    #pragma unroll
    for (int ks = 0; ks < 8; ++ks){
      f16x8 b = *(const f16x8*)&Ws[(sub*16 + lcol)*LDSK + quad*8 + ks*32];
      acc = __builtin_amdgcn_mfma_f32_16x16x32_f16(a[ks], b, acc, 0, 0, 0);
    }
    #pragma unroll
    for (int reg = 0; reg < 4; ++reg)
      out[(size_t)(i0 + wave*16 + quad*4 + reg)*HID + o0 + sub*16 + lcol] = (_Float16)acc[reg];
  }
}

__global__ __launch_bounds__(256) void prefix_kernel(const int* __restrict__ Bdeg,
                                                     int* __restrict__ off,
                                                     int* __restrict__ cursor){
  __shared__ int psum[256];
  __shared__ int excl[256];
  int t = threadIdx.x;
  int base = t * 64;
  int s = 0;
  for (int k = 0; k < 64; ++k) s += Bdeg[base + k];
  psum[t] = s;
  __syncthreads();
  if (t == 0){ int a = 0; for (int k = 0; k < 256; ++k){ excl[k] = a; a += psum[k]; } }
  __syncthreads();
  int a = excl[t];
  for (int k = 0; k < 64; ++k){ int dv = Bdeg[base + k]; off[base+k] = a; cursor[base+k] = a; a += dv; }
}

__global__ __launch_bounds__(256) void fill_kernel(const int* __restrict__ idx,
                                                   int* __restrict__ cursor,
                                                   int* __restrict__ rev){
  int i = blockIdx.x * 256 + threadIdx.x;
  #pragma unroll
  for (int t = 0; t < 4; ++t){
    int e = idx[i*4 + t];
    int p = atomicAdd(&cursor[e], 1);
    rev[p] = i;
  }
}

// E[e] = mean over contributing nodes of xt[node]  (gather via reverse CSR)
__global__ __launch_bounds__(256) void efeat_kernel(const _Float16* __restrict__ xt,
                                                    const int* __restrict__ off,
                                                    const int* __restrict__ deg,
                                                    const int* __restrict__ rev,
                                                    _Float16* __restrict__ E){
  int e = blockIdx.x, c = threadIdx.x;
  int o = off[e], d = deg[e];
  float s = 0.f;
  for (int k = 0; k < d; ++k) s += (float)xt[(size_t)rev[o + k]*HID + c];
  E[(size_t)e*HID + c] = (_Float16)((d > 0) ? s / (float)d : 0.f);
}

__global__ __launch_bounds__(256) void fin1_kernel(const _Float16* __restrict__ E,
                                                   const int* __restrict__ idx,
                                                   const float* __restrict__ b1,
                                                   const float* __restrict__ pa,
                                                   _Float16* __restrict__ h1){
  int i = blockIdx.x, c = threadIdx.x;
  const int* ip = idx + i*4;
  float s = (float)E[(size_t)ip[0]*HID + c] + (float)E[(size_t)ip[1]*HID + c]
          + (float)E[(size_t)ip[2]*HID + c] + (float)E[(size_t)ip[3]*HID + c];
  float acc = 0.25f * s + b1[c];
  float a = pa[0];
  acc = (acc >= 0.f) ? acc : a * acc;
  h1[(size_t)i*HID + c] = (_Float16)acc;
}

__global__ __launch_bounds__(256) void fin2_kernel(const _Float16* __restrict__ E,
                                                   const int* __restrict__ idx,
                                                   const float* __restrict__ b2,
                                                   const float* __restrict__ x,
                                                   const float* __restrict__ pa,
                                                   float* __restrict__ out){
  int i = blockIdx.x, c = threadIdx.x;
  const int* ip = idx + i*4;
  float s = (float)E[(size_t)ip[0]*HID + c] + (float)E[(size_t)ip[1]*HID + c]
          + (float)E[(size_t)ip[2]*HID + c] + (float)E[(size_t)ip[3]*HID + c];
  float acc = 0.25f * s + b2[c] + x[(size_t)i*HID + c];
  float a = pa[0];
  acc = (acc >= 0.f) ? acc : a * acc;
  out[(size_t)i*HID + c] = acc;
}

extern "C" void kernel_launch(void* const* d_in, const int* in_sizes, int n_in,
                              void* d_out, int out_size, void* d_ws, size_t ws_size,
                              hipStream_t stream){
  (void)in_sizes; (void)n_in; (void)out_size; (void)ws_size;
  const float* x  = (const float*)d_in[0];
  // d_in[1] = edge_index (int32), unused by the math
  const float* W1 = (const float*)d_in[2];
  const float* b1 = (const float*)d_in[3];
  const float* W2 = (const float*)d_in[4];
  const float* b2 = (const float*)d_in[5];
  const float* pa = (const float*)d_in[6];
  float* out = (float*)d_out;

  char* ws = (char*)d_ws;
  float*  sqf    = (float*) (ws + 0);                        //  64 KB
  int*    idx    = (int*)   (ws + 65536);                    // 256 KB
  int*    Bdeg   = (int*)   (ws + 327680);                   //  64 KB
  int*    offE   = (int*)   (ws + 393216);                   //  64 KB
  int*    cursor = (int*)   (ws + 458752);                   //  64 KB
  int*    rev    = (int*)   (ws + 524288);                   // 256 KB
  _Float16* xh   = (_Float16*)(ws + (size_t)(5<<20));        //   8 MB
  _Float16* W1h  = (_Float16*)(ws + (size_t)(13<<20));       // 128 KB
  _Float16* W2h  = (_Float16*)(ws + (size_t)(13<<20) + 131072);
  _Float16* xt   = (_Float16*)(ws + (size_t)(13<<20) + 262144);            // 8 MB
  _Float16* E    = (_Float16*)(ws + (size_t)(21<<20) + 262144);            // 8 MB
  _Float16* h1   = (_Float16*)(ws + (size_t)(29<<20) + 262144);            // 8 MB
  // candk (NN*64*4B = 4 MB) aliases the xt region: dead until the first
  // gemm_xw (which runs after rescore consumes it) -> no ws growth.
  unsigned* candk = (unsigned*)xt;                           // 4 MB

  hipMemsetAsync(Bdeg, 0, NN*sizeof(int), stream);
  prep_kernel   <<<CVTB + NN/16, 256, 0, stream>>>(x, W1, W2, xh, W1h, W2h, sqf);
  knn_kernel    <<<(NN/ITILE)*NSLICE, 256, 0, stream>>>(xh, sqf, candk);
  rescore_kernel<<<NN,      64, 0, stream>>>(x, sqf, candk, idx, Bdeg);
  prefix_kernel <<<1,      256, 0, stream>>>(Bdeg, offE, cursor);
  fill_kernel   <<<NN/256, 256, 0, stream>>>(idx, cursor, rev);

  gemm_xw       <<<(NN/64)*4, 256, 0, stream>>>(xh, W1h, xt);
  efeat_kernel  <<<NN,        256, 0, stream>>>(xt, offE, Bdeg, rev, E);
  fin1_kernel   <<<NN,        256, 0, stream>>>(E, idx, b1, pa, h1);

  gemm_xw       <<<(NN/64)*4, 256, 0, stream>>>(h1, W2h, xt);
  efeat_kernel  <<<NN,        256, 0, stream>>>(xt, offE, Bdeg, rev, E);
  fin2_kernel   <<<NN,        256, 0, stream>>>(E, idx, b2, x, pa, out);
}